// Round 8
// baseline (185.261 us; speedup 1.0000x reference)
//
#include <hip/hip_runtime.h>
#include <hip/hip_bf16.h>

typedef __attribute__((ext_vector_type(4))) float f32x4;
typedef __attribute__((ext_vector_type(4))) unsigned u32x4;
typedef __attribute__((ext_vector_type(8))) short bf16x8;

#define SCALE_F 0.03608439182435161f              // 768^-0.5
#define QSCALE  (0.03608439182435161f * 1.44269504088896f)  // scale * log2(e)

__device__ __forceinline__ unsigned short f2bf(float f) {
    union { float f; unsigned u; } v; v.f = f;
    return (unsigned short)((v.u + 0x7FFFu + ((v.u >> 16) & 1u)) >> 16);
}

__device__ __forceinline__ float fast_exp2(float x) {
#if __has_builtin(__builtin_amdgcn_exp2f)
    return __builtin_amdgcn_exp2f(x);
#else
    return exp2f(x);
#endif
}

__device__ __forceinline__ void gload_lds16(const void* g, void* l) {
    __builtin_amdgcn_global_load_lds(
        (const __attribute__((address_space(1))) unsigned int*)g,
        (__attribute__((address_space(3))) unsigned int*)l, 16, 0, 0);
}

// ---------------------------------------------------------------------------
// Prepass A: X fp32 -> bf16 (flat)
// ---------------------------------------------------------------------------
__global__ __launch_bounds__(256) void xcvt_kernel(const float* __restrict__ X,
                                                   unsigned short* __restrict__ Xb,
                                                   int n8) {
    const int i = blockIdx.x * 256 + threadIdx.x;
    if (i < n8) {
        f32x4 a = *(const f32x4*)(X + (size_t)i * 8);
        f32x4 b = *(const f32x4*)(X + (size_t)i * 8 + 4);
        bf16x8 w;
#pragma unroll
        for (int j = 0; j < 4; ++j) { w[j] = (short)f2bf(a[j]); w[4 + j] = (short)f2bf(b[j]); }
        *(bf16x8*)(Xb + (size_t)i * 8) = w;
    }
}

// ---------------------------------------------------------------------------
// Prepass B: W [R][C] fp32 -> WT [C][R] bf16   (R,C multiples of 64)
// ---------------------------------------------------------------------------
__global__ __launch_bounds__(256) void wtrans_kernel(const float* __restrict__ W,
                                                     unsigned short* __restrict__ WT,
                                                     int R, int C) {
    __shared__ unsigned short T[64][68];
    const int t = threadIdx.x;
    const int r0 = blockIdx.y * 64, c0 = blockIdx.x * 64;
    {
        const int lr = t >> 4, lc = (t & 15) * 4;
#pragma unroll
        for (int p = 0; p < 4; ++p) {
            const float* s = W + (size_t)(r0 + lr + p * 16) * C + c0 + lc;
            f32x4 v = *(const f32x4*)s;
            unsigned short* d = &T[lr + p * 16][lc];
            d[0] = f2bf(v[0]); d[1] = f2bf(v[1]); d[2] = f2bf(v[2]); d[3] = f2bf(v[3]);
        }
    }
    __syncthreads();
    {
        const int oc = t >> 3, j0 = (t & 7) * 8;
#pragma unroll
        for (int p = 0; p < 2; ++p) {
            const int c = oc + p * 32;
            bf16x8 v;
#pragma unroll
            for (int j = 0; j < 8; ++j) v[j] = (short)T[j0 + j][c];
            *(bf16x8*)(WT + (size_t)(c0 + c) * R + r0 + j0) = v;
        }
    }
}

// ---------------------------------------------------------------------------
// Kernel 1: QKV = Xb @ WqkvT^T + b  (M=8192, K=768, N=2304). Round-6 proven
// structure (single-buffer, __syncthreads, linear LDS). Q pre-scaled.
// ---------------------------------------------------------------------------
__global__ __launch_bounds__(256) void qkv_gemm_kernel(
    const unsigned short* __restrict__ Xb, const unsigned short* __restrict__ WT,
    const float* __restrict__ bias,
    unsigned short* __restrict__ Qw, unsigned short* __restrict__ Kw,
    unsigned short* __restrict__ VTw)
{
    __shared__ unsigned short Alds[128 * 32];  // [row][k] linear 64B rows
    __shared__ unsigned short Blds[128 * 32];  // [col][k] linear

    const int t = threadIdx.x;
    const int lane = t & 63, wave = t >> 6;
    const int l15 = lane & 15, l4 = lane >> 4;
    const int m0 = blockIdx.x * 128, n0 = blockIdx.y * 128;
    const int wr = wave >> 1, wc = wave & 1;

    f32x4 acc[4][4];
#pragma unroll
    for (int m = 0; m < 4; ++m)
#pragma unroll
        for (int n = 0; n < 4; ++n) acc[m][n] = (f32x4){0.f, 0.f, 0.f, 0.f};

    for (int k0 = 0; k0 < 768; k0 += 32) {
#pragma unroll
        for (int c = 0; c < 2; ++c) {
            const int o = wave * 1024 + lane * 16 + c * 4096;
            const int row = o >> 6, cb = o & 63;
            gload_lds16((const char*)(Xb + (size_t)(m0 + row) * 768 + k0) + cb,
                        (char*)Alds + wave * 1024 + c * 4096);
            gload_lds16((const char*)(WT + (size_t)(n0 + row) * 768 + k0) + cb,
                        (char*)Blds + wave * 1024 + c * 4096);
        }
        __syncthreads();
        bf16x8 af[4], bfr[4];
#pragma unroll
        for (int m = 0; m < 4; ++m)
            af[m] = *(const bf16x8*)((const char*)Alds + (wr * 64 + m * 16 + l15) * 64 + l4 * 16);
#pragma unroll
        for (int n = 0; n < 4; ++n)
            bfr[n] = *(const bf16x8*)((const char*)Blds + (wc * 64 + n * 16 + l15) * 64 + l4 * 16);
#pragma unroll
        for (int m = 0; m < 4; ++m)
#pragma unroll
            for (int n = 0; n < 4; ++n)
                acc[m][n] = __builtin_amdgcn_mfma_f32_16x16x32_bf16(af[m], bfr[n], acc[m][n], 0, 0, 0);
        __syncthreads();
    }

    // ---- epilogue: scatter into Q / K / V^T (bf16); Q pre-scaled
#pragma unroll
    for (int n = 0; n < 4; ++n) {
        const int col = n0 + wc * 64 + n * 16 + l15;       // 0..2303
        const float bv = bias[col];
        const int which = col / 768;                        // block-uniform
        const int cc = col - which * 768;
        const int h = cc >> 6, dd = cc & 63;
#pragma unroll
        for (int m = 0; m < 4; ++m) {
#pragma unroll
            for (int r = 0; r < 4; ++r) {
                const int row = m0 + wr * 64 + m * 16 + l4 * 4 + r;
                const int b = row >> 10, ntok = row & 1023;
                const size_t bh = (size_t)b * 12 + h;
                float val = acc[m][n][r] + bv;
                if (which == 0) val *= QSCALE;
                const unsigned short hv = f2bf(val);
                if (which == 0)      Qw[(bh * 1024 + ntok) * 64 + dd] = hv;
                else if (which == 1) Kw[(bh * 1024 + ntok) * 64 + dd] = hv;
                else                 VTw[(bh * 64 + dd) * 1024 + ntok] = hv;
            }
        }
    }
}

// ---------------------------------------------------------------------------
// Kernel 2: flash attention. 1 block = (bh, 64 q rows); 4 waves x 16 q rows.
// K: LDS triple-buffer (sigma-permuted rows, ONE barrier/iter).
// V: NO staging -- direct L2 reads into B-fragments (16B/lane), issued early
// so latency hides under QK^T+softmax. P stays in registers (sigma trick).
// ---------------------------------------------------------------------------
__global__ __launch_bounds__(256) void attn_kernel(
    const unsigned short* __restrict__ Qw, const unsigned short* __restrict__ Kw,
    const unsigned short* __restrict__ VTw, unsigned short* __restrict__ A2)
{
    __shared__ unsigned short Klds[3 * 64 * 64];    // 24KB: [buf][R][d] swizzled
    __shared__ float Flds[4 * 16];                  // per-wave row-stat bcast

    const int t = threadIdx.x, lane = t & 63, wave = t >> 6;
    const int l15 = lane & 15, l4 = lane >> 4;
    const int wg = (blockIdx.x & 7) * 192 + (blockIdx.x >> 3);
    const int qt = wg & 15, bh = wg >> 4;
    const int q0 = qt * 64;

    const size_t kvbase = (size_t)bh * 1024 * 64;
    const size_t vtbase = (size_t)bh * 64 * 1024;

    const unsigned short* qptr = Qw + kvbase + (size_t)(q0 + wave * 16 + l15) * 64;
    const bf16x8 qf0 = *(const bf16x8*)((const char*)qptr + l4 * 16);
    const bf16x8 qf1 = *(const bf16x8*)((const char*)qptr + 64 + l4 * 16);

    // V-fragment lane base: VT[d = df*16 + l15][kv0 + ks*32 + l4*8 .. +8]
    const unsigned short* vlane = VTw + vtbase + (size_t)l15 * 1024 + l4 * 8;

    f32x4 oacc[4];
#pragma unroll
    for (int d = 0; d < 4; ++d) oacc[d] = (f32x4){0.f, 0.f, 0.f, 0.f};
    float m_run = -1e30f, l_run = 0.f;

    auto STAGE_K = [&](int kt, int bufi) {
        const int kv0 = kt * 64;
        char* kb = (char*)Klds + bufi * 8192;
#pragma unroll
        for (int c = 0; c < 2; ++c) {
            const int oo = wave * 1024 + lane * 16 + c * 4096;
            const int R = oo >> 7, w = oo & 127;
            const int sw = w ^ ((R & 7) << 4);  // pre-swizzled source (m173)
            const int kvs = (R & 0x23) | ((R & 0x0C) << 1) | ((R & 0x10) >> 2);
            gload_lds16((const char*)(Kw + kvbase + (size_t)(kv0 + kvs) * 64) + sw,
                        kb + wave * 1024 + c * 4096);
        }
    };

    STAGE_K(0, 0);                      // 2 loads outstanding
    for (int kt = 0; kt < 16; ++kt) {
        // ---- issue V-fragment loads for THIS tile (8 x dwordx4, land under QK)
        bf16x8 vf[2][4];
#pragma unroll
        for (int ks = 0; ks < 2; ++ks)
#pragma unroll
            for (int df = 0; df < 4; ++df)
                vf[ks][df] = *(const bf16x8*)(vlane + df * 16384 + kt * 64 + ks * 32);
        // ---- stage next K tile; drain current K (hand-counted vmcnt)
        if (kt < 15) {
            STAGE_K(kt + 1, (kt + 1) % 3);
            __builtin_amdgcn_sched_barrier(0);
            asm volatile("s_waitcnt vmcnt(10)" ::: "memory");  // 2(Kcur)+8(V)+2(Knext)-2
        } else {
            __builtin_amdgcn_sched_barrier(0);
            asm volatile("s_waitcnt vmcnt(8)" ::: "memory");   // 2(Kcur)+8(V)-2
        }
        __builtin_amdgcn_s_barrier();   // all waves' K[cur] staged
        __builtin_amdgcn_sched_barrier(0);
        const char* kb = (const char*)Klds + (kt % 3) * 8192;

        // ---- S^T = K . Q^T : D[R][q], q=l15, R=kvf*16+l4*4+r (kv=sigma(R))
        f32x4 sacc[4];
#pragma unroll
        for (int i = 0; i < 4; ++i) sacc[i] = (f32x4){0.f, 0.f, 0.f, 0.f};
        __builtin_amdgcn_s_setprio(1);
#pragma unroll
        for (int ks = 0; ks < 2; ++ks) {
            const bf16x8 qq = ks ? qf1 : qf0;
#pragma unroll
            for (int kvf = 0; kvf < 4; ++kvf) {
                const int row = kvf * 16 + l15;
                int addr = row * 128 + ks * 64 + l4 * 16;
                addr ^= (row & 7) << 4;
                const bf16x8 kf = *(const bf16x8*)(kb + addr);
                sacc[kvf] = __builtin_amdgcn_mfma_f32_16x16x32_bf16(kf, qq, sacc[kvf], 0, 0, 0);
            }
        }
        __builtin_amdgcn_s_setprio(0);

        // ---- online softmax, exp2 domain, defer-max (THR=8 in log2 units)
        // p[ks*8+i] = P[q=l15][kv = ks*32 + l4*8 + i]  (thanks to sigma)
        float p[16];
        float tmax = -1e30f;
#pragma unroll
        for (int i = 0; i < 4; ++i)
#pragma unroll
            for (int r = 0; r < 4; ++r) {
                p[i * 4 + r] = sacc[i][r];
                tmax = fmaxf(tmax, sacc[i][r]);
            }
        tmax = fmaxf(tmax, __shfl_xor(tmax, 16));
        tmax = fmaxf(tmax, __shfl_xor(tmax, 32));

        if (!__all(tmax - m_run <= 8.f)) {
            const float mnew = fmaxf(m_run, tmax);
            const float alpha = fast_exp2(m_run - mnew);
            m_run = mnew;
            if (lane < 16) Flds[wave * 16 + lane] = alpha;
            const f32x4 av = *(const f32x4*)(&Flds[wave * 16 + l4 * 4]);
#pragma unroll
            for (int d = 0; d < 4; ++d)
#pragma unroll
                for (int r = 0; r < 4; ++r) oacc[d][r] *= av[r];
            l_run *= alpha;
        }

        float tsum = 0.f;
#pragma unroll
        for (int i = 0; i < 16; ++i) { p[i] = fast_exp2(p[i] - m_run); tsum += p[i]; }
        tsum += __shfl_xor(tsum, 16);
        tsum += __shfl_xor(tsum, 32);
        l_run += tsum;

        // ---- P -> bf16 A-fragments, fully in-register (8 cvt_pk)
        bf16x8 paf[2];
#pragma unroll
        for (int ks = 0; ks < 2; ++ks) {
            union { u32x4 u; bf16x8 h; } cv;
#pragma unroll
            for (int j2 = 0; j2 < 4; ++j2)
                asm("v_cvt_pk_bf16_f32 %0, %1, %2"
                    : "=v"(cv.u[j2]) : "v"(p[ks * 8 + 2 * j2]), "v"(p[ks * 8 + 2 * j2 + 1]));
            paf[ks] = cv.h;
        }

        // ---- O += P . V  (V already in registers; compiler waits vf's vmcnt)
        __builtin_amdgcn_s_setprio(1);
#pragma unroll
        for (int ks = 0; ks < 2; ++ks)
#pragma unroll
            for (int df = 0; df < 4; ++df)
                oacc[df] = __builtin_amdgcn_mfma_f32_16x16x32_bf16(paf[ks], vf[ks][df], oacc[df], 0, 0, 0);
        __builtin_amdgcn_s_setprio(0);
        // no second barrier: triple-buffered K restage is 2 barriers away
    }

    if (lane < 16) Flds[wave * 16 + lane] = 1.f / l_run;
    const f32x4 inv = *(const f32x4*)(&Flds[wave * 16 + l4 * 4]);
    const int b = bh / 12, h = bh - b * 12;
#pragma unroll
    for (int df = 0; df < 4; ++df) {
#pragma unroll
        for (int r = 0; r < 4; ++r) {
            const int row = b * 1024 + q0 + wave * 16 + l4 * 4 + r;
            const int col = h * 64 + df * 16 + l15;
            A2[(size_t)row * 768 + col] = f2bf(oacc[df][r] * inv[r]);
        }
    }
}

// ---------------------------------------------------------------------------
// Kernel 3: Out = A2 @ WoutT^T + b_out  (M=8192, K=768, N=768), fp32 out.
// 128x64 tile -> grid 64x12 = 768 blocks = 3/CU exactly (load-balanced).
// ---------------------------------------------------------------------------
__global__ __launch_bounds__(256) void out_gemm_kernel(
    const unsigned short* __restrict__ A2, const unsigned short* __restrict__ WT,
    const float* __restrict__ bias, float* __restrict__ Out)
{
    __shared__ unsigned short Alds[128 * 32];   // 8KB
    __shared__ unsigned short Blds[64 * 32];    // 4KB

    const int t = threadIdx.x;
    const int lane = t & 63, wave = t >> 6;
    const int l15 = lane & 15, l4 = lane >> 4;
    const int m0 = blockIdx.x * 128, n0 = blockIdx.y * 64;
    const int wr = wave >> 1, wc = wave & 1;

    f32x4 acc[4][2];
#pragma unroll
    for (int m = 0; m < 4; ++m)
#pragma unroll
        for (int n = 0; n < 2; ++n) acc[m][n] = (f32x4){0.f, 0.f, 0.f, 0.f};

    for (int k0 = 0; k0 < 768; k0 += 32) {
#pragma unroll
        for (int c = 0; c < 2; ++c) {
            const int o = wave * 1024 + lane * 16 + c * 4096;
            const int row = o >> 6, cb = o & 63;
            gload_lds16((const char*)(A2 + (size_t)(m0 + row) * 768 + k0) + cb,
                        (char*)Alds + wave * 1024 + c * 4096);
        }
        {
            const int o = t * 16;
            const int row = o >> 6, cb = o & 63;
            gload_lds16((const char*)(WT + (size_t)(n0 + row) * 768 + k0) + cb,
                        (char*)Blds + o);
        }
        __syncthreads();
        bf16x8 af[4], bfr[2];
#pragma unroll
        for (int m = 0; m < 4; ++m)
            af[m] = *(const bf16x8*)((const char*)Alds + (wr * 64 + m * 16 + l15) * 64 + l4 * 16);
#pragma unroll
        for (int n = 0; n < 2; ++n)
            bfr[n] = *(const bf16x8*)((const char*)Blds + (wc * 32 + n * 16 + l15) * 64 + l4 * 16);
#pragma unroll
        for (int m = 0; m < 4; ++m)
#pragma unroll
            for (int n = 0; n < 2; ++n)
                acc[m][n] = __builtin_amdgcn_mfma_f32_16x16x32_bf16(af[m], bfr[n], acc[m][n], 0, 0, 0);
        __syncthreads();
    }

#pragma unroll
    for (int n = 0; n < 2; ++n) {
        const int col = n0 + wc * 32 + n * 16 + l15;
        const float bv = bias[col];
#pragma unroll
        for (int m = 0; m < 4; ++m)
#pragma unroll
            for (int r = 0; r < 4; ++r) {
                const int row = m0 + wr * 64 + m * 16 + l4 * 4 + r;
                Out[(size_t)row * 768 + col] = acc[m][n][r] + bv;
            }
    }
}

// ---------------------------------------------------------------------------
extern "C" void kernel_launch(void* const* d_in, const int* in_sizes, int n_in,
                              void* d_out, int out_size, void* d_ws, size_t ws_size,
                              hipStream_t stream) {
    const float* X    = (const float*)d_in[0];
    const float* Wqkv = (const float*)d_in[1];
    const float* bqkv = (const float*)d_in[2];
    const float* Wout = (const float*)d_in[3];
    const float* bout = (const float*)d_in[4];
    float* Out = (float*)d_out;

    const size_t nq = (size_t)96 * 1024 * 64;   // 6291456 elems (12.58 MB bf16)
    unsigned short* XbA2  = (unsigned short*)d_ws;       // Xb, later reused as A2
    unsigned short* Qw    = XbA2 + nq;
    unsigned short* Kw    = Qw + nq;
    unsigned short* VTw   = Kw + nq;
    unsigned short* WqkvT = VTw + nq;                    // 2304*768
    unsigned short* WoutT = WqkvT + (size_t)2304 * 768;  // 768*768; total 55.1 MB

    hipLaunchKernelGGL(xcvt_kernel, dim3(3072), dim3(256), 0, stream,
                       X, XbA2, 8192 * 768 / 8);
    hipLaunchKernelGGL(wtrans_kernel, dim3(36, 12), dim3(256), 0, stream,
                       Wqkv, WqkvT, 768, 2304);
    hipLaunchKernelGGL(wtrans_kernel, dim3(12, 12), dim3(256), 0, stream,
                       Wout, WoutT, 768, 768);
    hipLaunchKernelGGL(qkv_gemm_kernel, dim3(64, 18), dim3(256), 0, stream,
                       XbA2, WqkvT, bqkv, Qw, Kw, VTw);
    hipLaunchKernelGGL(attn_kernel, dim3(1536), dim3(256), 0, stream,
                       Qw, Kw, VTw, XbA2);
    hipLaunchKernelGGL(out_gemm_kernel, dim3(64, 12), dim3(256), 0, stream,
                       XbA2, WoutT, bout, Out);
}

// Round 9
// 137.717 us; speedup vs baseline: 1.3452x; 1.3452x over previous
//
#include <hip/hip_runtime.h>
#include <hip/hip_bf16.h>

typedef __attribute__((ext_vector_type(4))) float f32x4;
typedef __attribute__((ext_vector_type(4))) unsigned u32x4;
typedef __attribute__((ext_vector_type(8))) short bf16x8;

#define SCALE_F 0.03608439182435161f              // 768^-0.5
#define QSCALE  (0.03608439182435161f * 1.44269504088896f)  // scale * log2(e)

__device__ __forceinline__ unsigned short f2bf(float f) {
    union { float f; unsigned u; } v; v.f = f;
    return (unsigned short)((v.u + 0x7FFFu + ((v.u >> 16) & 1u)) >> 16);
}

__device__ __forceinline__ float fast_exp2(float x) {
#if __has_builtin(__builtin_amdgcn_exp2f)
    return __builtin_amdgcn_exp2f(x);
#else
    return exp2f(x);
#endif
}

__device__ __forceinline__ void gload_lds16(const void* g, void* l) {
    __builtin_amdgcn_global_load_lds(
        (const __attribute__((address_space(1))) unsigned int*)g,
        (__attribute__((address_space(3))) unsigned int*)l, 16, 0, 0);
}

// ---------------------------------------------------------------------------
// Prepass A: X fp32 -> bf16 (flat)
// ---------------------------------------------------------------------------
__global__ __launch_bounds__(256) void xcvt_kernel(const float* __restrict__ X,
                                                   unsigned short* __restrict__ Xb,
                                                   int n8) {
    const int i = blockIdx.x * 256 + threadIdx.x;
    if (i < n8) {
        f32x4 a = *(const f32x4*)(X + (size_t)i * 8);
        f32x4 b = *(const f32x4*)(X + (size_t)i * 8 + 4);
        bf16x8 w;
#pragma unroll
        for (int j = 0; j < 4; ++j) { w[j] = (short)f2bf(a[j]); w[4 + j] = (short)f2bf(b[j]); }
        *(bf16x8*)(Xb + (size_t)i * 8) = w;
    }
}

// ---------------------------------------------------------------------------
// Prepass B: W [R][C] fp32 -> WT [C][R] bf16   (R,C multiples of 64)
// ---------------------------------------------------------------------------
__global__ __launch_bounds__(256) void wtrans_kernel(const float* __restrict__ W,
                                                     unsigned short* __restrict__ WT,
                                                     int R, int C) {
    __shared__ unsigned short T[64][68];
    const int t = threadIdx.x;
    const int r0 = blockIdx.y * 64, c0 = blockIdx.x * 64;
    {
        const int lr = t >> 4, lc = (t & 15) * 4;
#pragma unroll
        for (int p = 0; p < 4; ++p) {
            const float* s = W + (size_t)(r0 + lr + p * 16) * C + c0 + lc;
            f32x4 v = *(const f32x4*)s;
            unsigned short* d = &T[lr + p * 16][lc];
            d[0] = f2bf(v[0]); d[1] = f2bf(v[1]); d[2] = f2bf(v[2]); d[3] = f2bf(v[3]);
        }
    }
    __syncthreads();
    {
        const int oc = t >> 3, j0 = (t & 7) * 8;
#pragma unroll
        for (int p = 0; p < 2; ++p) {
            const int c = oc + p * 32;
            bf16x8 v;
#pragma unroll
            for (int j = 0; j < 8; ++j) v[j] = (short)T[j0 + j][c];
            *(bf16x8*)(WT + (size_t)(c0 + c) * R + r0 + j0) = v;
        }
    }
}

// ---------------------------------------------------------------------------
// Kernel 1: QKV = Xb @ WqkvT^T + b  (M=8192, K=768, N=2304). Round-6 proven
// structure (single-buffer, __syncthreads, linear LDS). Q pre-scaled.
// ---------------------------------------------------------------------------
__global__ __launch_bounds__(256) void qkv_gemm_kernel(
    const unsigned short* __restrict__ Xb, const unsigned short* __restrict__ WT,
    const float* __restrict__ bias,
    unsigned short* __restrict__ Qw, unsigned short* __restrict__ Kw,
    unsigned short* __restrict__ VTw)
{
    __shared__ unsigned short Alds[128 * 32];  // [row][k] linear 64B rows
    __shared__ unsigned short Blds[128 * 32];  // [col][k] linear

    const int t = threadIdx.x;
    const int lane = t & 63, wave = t >> 6;
    const int l15 = lane & 15, l4 = lane >> 4;
    const int m0 = blockIdx.x * 128, n0 = blockIdx.y * 128;
    const int wr = wave >> 1, wc = wave & 1;

    f32x4 acc[4][4];
#pragma unroll
    for (int m = 0; m < 4; ++m)
#pragma unroll
        for (int n = 0; n < 4; ++n) acc[m][n] = (f32x4){0.f, 0.f, 0.f, 0.f};

    for (int k0 = 0; k0 < 768; k0 += 32) {
#pragma unroll
        for (int c = 0; c < 2; ++c) {
            const int o = wave * 1024 + lane * 16 + c * 4096;
            const int row = o >> 6, cb = o & 63;
            gload_lds16((const char*)(Xb + (size_t)(m0 + row) * 768 + k0) + cb,
                        (char*)Alds + wave * 1024 + c * 4096);
            gload_lds16((const char*)(WT + (size_t)(n0 + row) * 768 + k0) + cb,
                        (char*)Blds + wave * 1024 + c * 4096);
        }
        __syncthreads();
        bf16x8 af[4], bfr[4];
#pragma unroll
        for (int m = 0; m < 4; ++m)
            af[m] = *(const bf16x8*)((const char*)Alds + (wr * 64 + m * 16 + l15) * 64 + l4 * 16);
#pragma unroll
        for (int n = 0; n < 4; ++n)
            bfr[n] = *(const bf16x8*)((const char*)Blds + (wc * 64 + n * 16 + l15) * 64 + l4 * 16);
#pragma unroll
        for (int m = 0; m < 4; ++m)
#pragma unroll
            for (int n = 0; n < 4; ++n)
                acc[m][n] = __builtin_amdgcn_mfma_f32_16x16x32_bf16(af[m], bfr[n], acc[m][n], 0, 0, 0);
        __syncthreads();
    }

    // ---- epilogue: scatter into Q / K / V^T (bf16); Q pre-scaled
#pragma unroll
    for (int n = 0; n < 4; ++n) {
        const int col = n0 + wc * 64 + n * 16 + l15;       // 0..2303
        const float bv = bias[col];
        const int which = col / 768;                        // block-uniform
        const int cc = col - which * 768;
        const int h = cc >> 6, dd = cc & 63;
#pragma unroll
        for (int m = 0; m < 4; ++m) {
#pragma unroll
            for (int r = 0; r < 4; ++r) {
                const int row = m0 + wr * 64 + m * 16 + l4 * 4 + r;
                const int b = row >> 10, ntok = row & 1023;
                const size_t bh = (size_t)b * 12 + h;
                float val = acc[m][n][r] + bv;
                if (which == 0) val *= QSCALE;
                const unsigned short hv = f2bf(val);
                if (which == 0)      Qw[(bh * 1024 + ntok) * 64 + dd] = hv;
                else if (which == 1) Kw[(bh * 1024 + ntok) * 64 + dd] = hv;
                else                 VTw[(bh * 64 + dd) * 1024 + ntok] = hv;
            }
        }
    }
}

// ---------------------------------------------------------------------------
// Kernel 2: flash attention (round-6 proven). 1 block = (bh, 64 q rows).
// Swapped QK^T with SIGMA-PERMUTED K rows -> P stays in registers.
// K+V LDS double-buffer, counted vmcnt(4), exp2 softmax, defer-max,
// XCD-bijective swizzle, setprio on MFMA clusters.
// ---------------------------------------------------------------------------
__global__ __launch_bounds__(256) void attn_kernel(
    const unsigned short* __restrict__ Qw, const unsigned short* __restrict__ Kw,
    const unsigned short* __restrict__ VTw, unsigned short* __restrict__ A2)
{
    __shared__ unsigned short Klds[2 * 64 * 64];    // [buf][R][d] swizzled, R=sigma'd kv
    __shared__ unsigned short Vlds[2 * 64 * 64];    // [buf][d][kv] swizzled
    __shared__ float Flds[4 * 16];                  // per-wave row-stat bcast

    const int t = threadIdx.x, lane = t & 63, wave = t >> 6;
    const int l15 = lane & 15, l4 = lane >> 4;
    const int wg = (blockIdx.x & 7) * 192 + (blockIdx.x >> 3);
    const int qt = wg & 15, bh = wg >> 4;
    const int q0 = qt * 64;

    const size_t kvbase = (size_t)bh * 1024 * 64;
    const size_t vtbase = (size_t)bh * 64 * 1024;

    const unsigned short* qptr = Qw + kvbase + (size_t)(q0 + wave * 16 + l15) * 64;
    const bf16x8 qf0 = *(const bf16x8*)((const char*)qptr + l4 * 16);
    const bf16x8 qf1 = *(const bf16x8*)((const char*)qptr + 64 + l4 * 16);

    f32x4 oacc[4];
#pragma unroll
    for (int d = 0; d < 4; ++d) oacc[d] = (f32x4){0.f, 0.f, 0.f, 0.f};
    float m_run = -1e30f, l_run = 0.f;

    auto STAGE = [&](int kt, int bufi) {
        const int kv0 = kt * 64;
        char* kb = (char*)Klds + bufi * 8192;
        char* vb = (char*)Vlds + bufi * 8192;
#pragma unroll
        for (int c = 0; c < 2; ++c) {
            const int oo = wave * 1024 + lane * 16 + c * 4096;
            const int R = oo >> 7, w = oo & 127;
            const int sw = w ^ ((R & 7) << 4);  // pre-swizzled source (m173)
            const int kvs = (R & 0x23) | ((R & 0x0C) << 1) | ((R & 0x10) >> 2);
            gload_lds16((const char*)(Kw + kvbase + (size_t)(kv0 + kvs) * 64) + sw,
                        kb + wave * 1024 + c * 4096);
            gload_lds16((const char*)(VTw + vtbase + (size_t)R * 1024 + kv0) + sw,
                        vb + wave * 1024 + c * 4096);
        }
    };

    STAGE(0, 0);
    for (int kt = 0; kt < 16; ++kt) {
        const int cur = kt & 1;
        if (kt < 15) {
            STAGE(kt + 1, cur ^ 1);
            asm volatile("s_waitcnt vmcnt(4)" ::: "memory");
        } else {
            asm volatile("s_waitcnt vmcnt(0)" ::: "memory");
        }
        __builtin_amdgcn_s_barrier();
        __builtin_amdgcn_sched_barrier(0);
        const char* kb = (const char*)Klds + cur * 8192;
        const char* vb = (const char*)Vlds + cur * 8192;

        // ---- S^T = K . Q^T : D[R][q], q=l15, R=kvf*16+l4*4+r (kv=sigma(R))
        f32x4 sacc[4];
#pragma unroll
        for (int i = 0; i < 4; ++i) sacc[i] = (f32x4){0.f, 0.f, 0.f, 0.f};
        __builtin_amdgcn_s_setprio(1);
#pragma unroll
        for (int ks = 0; ks < 2; ++ks) {
            const bf16x8 qq = ks ? qf1 : qf0;
#pragma unroll
            for (int kvf = 0; kvf < 4; ++kvf) {
                const int row = kvf * 16 + l15;
                int addr = row * 128 + ks * 64 + l4 * 16;
                addr ^= (row & 7) << 4;
                const bf16x8 kf = *(const bf16x8*)(kb + addr);
                sacc[kvf] = __builtin_amdgcn_mfma_f32_16x16x32_bf16(kf, qq, sacc[kvf], 0, 0, 0);
            }
        }
        __builtin_amdgcn_s_setprio(0);

        // ---- online softmax, exp2 domain, defer-max (THR=8 in log2 units)
        // p[ks*8+i] = P[q=l15][kv = ks*32 + l4*8 + i]  (thanks to sigma)
        float p[16];
        float tmax = -1e30f;
#pragma unroll
        for (int i = 0; i < 4; ++i)
#pragma unroll
            for (int r = 0; r < 4; ++r) {
                p[i * 4 + r] = sacc[i][r];
                tmax = fmaxf(tmax, sacc[i][r]);
            }
        tmax = fmaxf(tmax, __shfl_xor(tmax, 16));
        tmax = fmaxf(tmax, __shfl_xor(tmax, 32));

        if (!__all(tmax - m_run <= 8.f)) {
            const float mnew = fmaxf(m_run, tmax);
            const float alpha = fast_exp2(m_run - mnew);
            m_run = mnew;
            if (lane < 16) Flds[wave * 16 + lane] = alpha;
            const f32x4 av = *(const f32x4*)(&Flds[wave * 16 + l4 * 4]);
#pragma unroll
            for (int d = 0; d < 4; ++d)
#pragma unroll
                for (int r = 0; r < 4; ++r) oacc[d][r] *= av[r];
            l_run *= alpha;
        }

        float tsum = 0.f;
#pragma unroll
        for (int i = 0; i < 16; ++i) { p[i] = fast_exp2(p[i] - m_run); tsum += p[i]; }
        tsum += __shfl_xor(tsum, 16);
        tsum += __shfl_xor(tsum, 32);
        l_run += tsum;

        // ---- P -> bf16 A-fragments, fully in-register (8 cvt_pk)
        bf16x8 paf[2];
#pragma unroll
        for (int ks = 0; ks < 2; ++ks) {
            union { u32x4 u; bf16x8 h; } cv;
#pragma unroll
            for (int j2 = 0; j2 < 4; ++j2)
                asm("v_cvt_pk_bf16_f32 %0, %1, %2"
                    : "=v"(cv.u[j2]) : "v"(p[ks * 8 + 2 * j2]), "v"(p[ks * 8 + 2 * j2 + 1]));
            paf[ks] = cv.h;
        }

        // ---- O += P . V  (A=P rows q, B=V[kv][d] read from V^T rows)
        __builtin_amdgcn_s_setprio(1);
#pragma unroll
        for (int ks = 0; ks < 2; ++ks) {
#pragma unroll
            for (int df = 0; df < 4; ++df) {
                const int d = df * 16 + l15;
                int addr = d * 128 + ks * 64 + l4 * 16;
                addr ^= (d & 7) << 4;
                const bf16x8 vf = *(const bf16x8*)(vb + addr);
                oacc[df] = __builtin_amdgcn_mfma_f32_16x16x32_bf16(paf[ks], vf, oacc[df], 0, 0, 0);
            }
        }
        __builtin_amdgcn_s_setprio(0);
        __builtin_amdgcn_s_barrier();
    }

    if (lane < 16) Flds[wave * 16 + lane] = 1.f / l_run;
    const f32x4 inv = *(const f32x4*)(&Flds[wave * 16 + l4 * 4]);
    const int b = bh / 12, h = bh - b * 12;
#pragma unroll
    for (int df = 0; df < 4; ++df) {
#pragma unroll
        for (int r = 0; r < 4; ++r) {
            const int row = b * 1024 + q0 + wave * 16 + l4 * 4 + r;
            const int col = h * 64 + df * 16 + l15;
            A2[(size_t)row * 768 + col] = f2bf(oacc[df][r] * inv[r]);
        }
    }
}

// ---------------------------------------------------------------------------
// Kernel 3: Out = A2 @ WoutT^T + b_out  (M=8192, K=768, N=768), fp32 out.
// 128x64 tile -> grid 64x12 = 768 blocks = 3/CU exactly (load-balanced).
// ---------------------------------------------------------------------------
__global__ __launch_bounds__(256) void out_gemm_kernel(
    const unsigned short* __restrict__ A2, const unsigned short* __restrict__ WT,
    const float* __restrict__ bias, float* __restrict__ Out)
{
    __shared__ unsigned short Alds[128 * 32];   // 8KB
    __shared__ unsigned short Blds[64 * 32];    // 4KB

    const int t = threadIdx.x;
    const int lane = t & 63, wave = t >> 6;
    const int l15 = lane & 15, l4 = lane >> 4;
    const int m0 = blockIdx.x * 128, n0 = blockIdx.y * 64;
    const int wr = wave >> 1, wc = wave & 1;

    f32x4 acc[4][2];
#pragma unroll
    for (int m = 0; m < 4; ++m)
#pragma unroll
        for (int n = 0; n < 2; ++n) acc[m][n] = (f32x4){0.f, 0.f, 0.f, 0.f};

    for (int k0 = 0; k0 < 768; k0 += 32) {
#pragma unroll
        for (int c = 0; c < 2; ++c) {
            const int o = wave * 1024 + lane * 16 + c * 4096;
            const int row = o >> 6, cb = o & 63;
            gload_lds16((const char*)(A2 + (size_t)(m0 + row) * 768 + k0) + cb,
                        (char*)Alds + wave * 1024 + c * 4096);
        }
        {
            const int o = t * 16;
            const int row = o >> 6, cb = o & 63;
            gload_lds16((const char*)(WT + (size_t)(n0 + row) * 768 + k0) + cb,
                        (char*)Blds + o);
        }
        __syncthreads();
        bf16x8 af[4], bfr[2];
#pragma unroll
        for (int m = 0; m < 4; ++m)
            af[m] = *(const bf16x8*)((const char*)Alds + (wr * 64 + m * 16 + l15) * 64 + l4 * 16);
#pragma unroll
        for (int n = 0; n < 2; ++n)
            bfr[n] = *(const bf16x8*)((const char*)Blds + (wc * 32 + n * 16 + l15) * 64 + l4 * 16);
#pragma unroll
        for (int m = 0; m < 4; ++m)
#pragma unroll
            for (int n = 0; n < 2; ++n)
                acc[m][n] = __builtin_amdgcn_mfma_f32_16x16x32_bf16(af[m], bfr[n], acc[m][n], 0, 0, 0);
        __syncthreads();
    }

#pragma unroll
    for (int n = 0; n < 2; ++n) {
        const int col = n0 + wc * 32 + n * 16 + l15;
        const float bv = bias[col];
#pragma unroll
        for (int m = 0; m < 4; ++m)
#pragma unroll
            for (int r = 0; r < 4; ++r) {
                const int row = m0 + wr * 64 + m * 16 + l4 * 4 + r;
                Out[(size_t)row * 768 + col] = acc[m][n][r] + bv;
            }
    }
}

// ---------------------------------------------------------------------------
extern "C" void kernel_launch(void* const* d_in, const int* in_sizes, int n_in,
                              void* d_out, int out_size, void* d_ws, size_t ws_size,
                              hipStream_t stream) {
    const float* X    = (const float*)d_in[0];
    const float* Wqkv = (const float*)d_in[1];
    const float* bqkv = (const float*)d_in[2];
    const float* Wout = (const float*)d_in[3];
    const float* bout = (const float*)d_in[4];
    float* Out = (float*)d_out;

    const size_t nq = (size_t)96 * 1024 * 64;   // 6291456 elems (12.58 MB bf16)
    unsigned short* XbA2  = (unsigned short*)d_ws;       // Xb, later reused as A2
    unsigned short* Qw    = XbA2 + nq;
    unsigned short* Kw    = Qw + nq;
    unsigned short* VTw   = Kw + nq;
    unsigned short* WqkvT = VTw + nq;                    // 2304*768
    unsigned short* WoutT = WqkvT + (size_t)2304 * 768;  // 768*768; total 55.1 MB

    hipLaunchKernelGGL(xcvt_kernel, dim3(3072), dim3(256), 0, stream,
                       X, XbA2, 8192 * 768 / 8);
    hipLaunchKernelGGL(wtrans_kernel, dim3(36, 12), dim3(256), 0, stream,
                       Wqkv, WqkvT, 768, 2304);
    hipLaunchKernelGGL(wtrans_kernel, dim3(12, 12), dim3(256), 0, stream,
                       Wout, WoutT, 768, 768);
    hipLaunchKernelGGL(qkv_gemm_kernel, dim3(64, 18), dim3(256), 0, stream,
                       XbA2, WqkvT, bqkv, Qw, Kw, VTw);
    hipLaunchKernelGGL(attn_kernel, dim3(1536), dim3(256), 0, stream,
                       Qw, Kw, VTw, XbA2);
    hipLaunchKernelGGL(out_gemm_kernel, dim3(64, 12), dim3(256), 0, stream,
                       XbA2, WoutT, bout, Out);
}